// Round 1
// baseline (3275.001 us; speedup 1.0000x reference)
//
#include <hip/hip_runtime.h>
#include <cstdint>
#include <cstddef>

// Problem shape (fixed by the reference): E=1.6M, D=64, H=128, N=100k.
#define D_FEAT 64
#define H_HID 128

// ---------------------------------------------------------------------------
// Kernel 1: scatter-add edge_attr into flow[future] and flow[past].
// One thread per (edge, group-of-4-features): coalesced float4 read of
// edge_attr; 8 global_atomic_add_f32 per thread (4 floats x 2 endpoints).
// 16 consecutive lanes cover one node's contiguous 256B row.
// ---------------------------------------------------------------------------
__global__ __launch_bounds__(256) void scatter_kernel(
    const int* __restrict__ idx,      // [2*E], row 0 = past, row 1 = future
    const float* __restrict__ attr,   // [E, 64]
    float* __restrict__ flow,         // [N, 64] accumulator (pre-zeroed)
    int E) {
  int t = blockIdx.x * 256 + threadIdx.x;   // t in [0, E*16)
  int e = t >> 4;
  if (e >= E) return;
  int g = t & 15;

  float4 v = reinterpret_cast<const float4*>(attr)[t];
  int past   = idx[e];
  int future = idx[E + e];

  float* fdst = flow + (size_t)future * D_FEAT + g * 4;
  float* pdst = flow + (size_t)past   * D_FEAT + g * 4;

  // Hardware fp32 atomics (global_atomic_add_f32); flow region (25.6MB) is
  // L2/L3 resident so these execute cache-side.
  unsafeAtomicAdd(fdst + 0, v.x);
  unsafeAtomicAdd(fdst + 1, v.y);
  unsafeAtomicAdd(fdst + 2, v.z);
  unsafeAtomicAdd(fdst + 3, v.w);
  unsafeAtomicAdd(pdst + 0, v.x);
  unsafeAtomicAdd(pdst + 1, v.y);
  unsafeAtomicAdd(pdst + 2, v.z);
  unsafeAtomicAdd(pdst + 3, v.w);
}

// ---------------------------------------------------------------------------
// Kernel 2: per-node MLP  out = relu(flow @ W1 + b1) @ W2 + b2.
// Thread-per-node. W1 in LDS natural layout [64][128] (phase-1 reads are
// contiguous in k -> ds_read_b128). W2 staged TRANSPOSED [64][128]
// (sW2t[j][k] = W2[k][j]) so phase-2 reads are contiguous in k too.
// h[128] kept in registers; inner k-loops fully unrolled (constant register
// indices), outer i/j loops dynamic (small code size, no spills).
// LDS = 2 * 32KB = 64KB exactly -> 2 blocks/CU.
// ---------------------------------------------------------------------------
__global__ __launch_bounds__(256) void mlp_kernel(
    const float* __restrict__ flow,   // [N, 64]
    const float* __restrict__ W1,     // [64, 128]
    const float* __restrict__ b1,     // [128]
    const float* __restrict__ W2,     // [128, 64]
    const float* __restrict__ b2,     // [64]
    float* __restrict__ out,          // [N, 64]
    int N) {
  __shared__ float sW1[D_FEAT * H_HID];   // [i][k], natural
  __shared__ float sW2t[D_FEAT * H_HID];  // [j][k], transposed W2

  // Cooperative stage: W1 linear (coalesced, conflict-free writes).
  {
    float4* dst = reinterpret_cast<float4*>(sW1);
    const float4* src = reinterpret_cast<const float4*>(W1);
    for (int i = threadIdx.x; i < (D_FEAT * H_HID) / 4; i += 256) dst[i] = src[i];
  }
  // W2 transpose: read coalesced, write strided (one-time 32-way write
  // conflict per wave -- negligible vs the main loop).
  for (int t = threadIdx.x; t < H_HID * D_FEAT; t += 256) {
    int k = t >> 6;          // 0..127
    int j = t & 63;          // 0..63
    sW2t[j * H_HID + k] = W2[t];
  }
  __syncthreads();

  int n = blockIdx.x * 256 + threadIdx.x;
  if (n >= N) return;

  const float* x = flow + (size_t)n * D_FEAT;

  // Phase 1: h = x @ W1 + b1   (h[128] in registers)
  float h[H_HID];
#pragma unroll
  for (int k = 0; k < H_HID; ++k) h[k] = b1[k];

  for (int i = 0; i < D_FEAT; ++i) {     // dynamic loop
    float xi = x[i];
    const float* w = &sW1[i * H_HID];
#pragma unroll
    for (int k = 0; k < H_HID; ++k) h[k] += xi * w[k];   // 32x ds_read_b128
  }

  // ReLU
#pragma unroll
  for (int k = 0; k < H_HID; ++k) h[k] = fmaxf(h[k], 0.0f);

  // Phase 2: out[j] = h @ W2[:,j] + b2[j], one j per iteration (dynamic).
  float* outn = out + (size_t)n * D_FEAT;
  for (int j = 0; j < D_FEAT; ++j) {     // dynamic loop
    float acc = b2[j];
    const float* w = &sW2t[j * H_HID];
#pragma unroll
    for (int k = 0; k < H_HID; ++k) acc += h[k] * w[k];  // 32x ds_read_b128
    outn[j] = acc;
  }
}

// ---------------------------------------------------------------------------
// Launch
// ---------------------------------------------------------------------------
extern "C" void kernel_launch(void* const* d_in, const int* in_sizes, int n_in,
                              void* d_out, int out_size, void* d_ws, size_t ws_size,
                              hipStream_t stream) {
  const int*   edge_index = (const int*)d_in[0];    // [2, E] int32
  const float* edge_attr  = (const float*)d_in[1];  // [E, 64]
  const float* W1         = (const float*)d_in[3];  // [64, 128]
  const float* b1         = (const float*)d_in[4];  // [128]
  const float* W2         = (const float*)d_in[5];  // [128, 64]
  const float* b2         = (const float*)d_in[6];  // [64]
  float* out = (float*)d_out;

  const int E = in_sizes[1] / D_FEAT;               // 1,600,000
  const int N = out_size / D_FEAT;                  // 100,000

  float* flow = (float*)d_ws;                       // [N, 64] accumulator

  // d_ws is re-poisoned 0xAA before every timed launch -> must zero each call.
  hipMemsetAsync(flow, 0, (size_t)N * D_FEAT * sizeof(float), stream);

  // Scatter: E*16 threads.
  {
    long long total = (long long)E * 16;
    int blocks = (int)((total + 255) / 256);
    scatter_kernel<<<blocks, 256, 0, stream>>>(edge_index, edge_attr, flow, E);
  }

  // MLP: one thread per node.
  {
    int blocks = (N + 255) / 256;
    mlp_kernel<<<blocks, 256, 0, stream>>>(flow, W1, b1, W2, b2, out, N);
  }
}

// Round 2
// 1772.258 us; speedup vs baseline: 1.8479x; 1.8479x over previous
//
#include <hip/hip_runtime.h>
#include <cstdint>
#include <cstddef>

// Problem shape (fixed by the reference): E=1.6M, D=64, H=128, N=100k.
#define D_FEAT 64
#define H_HID 128
#define SCAN_T 1024
#define SCAN_PER 8

// ---------------------------------------------------------------------------
// Workspace layout (13.6 MB total):
//   deg   : int[N]    per-node incidence count
//   off   : int[N]    exclusive start offsets; fill_kernel advances them to
//                     END offsets (cursor trick), gather uses off[n]-deg[n]
//   elist : int[2E]   edge id per incidence (CSR column array)
// ---------------------------------------------------------------------------

// 1. Count incidences: 3.2M int atomics into 100k L2-resident counters.
__global__ __launch_bounds__(256) void count_deg_kernel(
    const int* __restrict__ idx, int* __restrict__ deg, int twoE) {
  int t = blockIdx.x * 256 + threadIdx.x;
  if (t < twoE) atomicAdd(&deg[idx[t]], 1);
}

// 2. Exclusive prefix scan of deg -> off. Single workgroup, serial over
// chunks of 8192 with a running carry; Hillis-Steele scan of per-thread sums.
__global__ __launch_bounds__(SCAN_T) void scan_kernel(
    const int* __restrict__ deg, int* __restrict__ off, int N) {
  __shared__ int lsum[SCAN_T];
  int carry = 0;
  int nchunk = (N + SCAN_T * SCAN_PER - 1) / (SCAN_T * SCAN_PER);
  for (int c = 0; c < nchunk; ++c) {
    int base = c * SCAN_T * SCAN_PER + threadIdx.x * SCAN_PER;
    int v[SCAN_PER];
    int s = 0;
#pragma unroll
    for (int j = 0; j < SCAN_PER; ++j) {
      int i = base + j;
      v[j] = (i < N) ? deg[i] : 0;
      s += v[j];
    }
    lsum[threadIdx.x] = s;
    __syncthreads();
    for (int d = 1; d < SCAN_T; d <<= 1) {
      int x = (threadIdx.x >= d) ? lsum[threadIdx.x - d] : 0;
      __syncthreads();
      lsum[threadIdx.x] += x;
      __syncthreads();
    }
    int run = carry + lsum[threadIdx.x] - s;  // exclusive position
#pragma unroll
    for (int j = 0; j < SCAN_PER; ++j) {
      int i = base + j;
      if (i < N) off[i] = run;
      run += v[j];
    }
    carry += lsum[SCAN_T - 1];
    __syncthreads();  // protect lsum before next chunk overwrites
  }
}

// 3. Fill adjacency. atomicAdd on off[] itself (destructive cursor): after
// this kernel off[n] == end of node n's segment; start = off[n] - deg[n].
__global__ __launch_bounds__(256) void fill_kernel(
    const int* __restrict__ idx, int* __restrict__ off,
    int* __restrict__ elist, int E) {
  int t = blockIdx.x * 256 + threadIdx.x;
  if (t >= 2 * E) return;
  int node = idx[t];
  int e = (t < E) ? t : t - E;  // edge id; endpoint identity irrelevant (sum)
  int pos = atomicAdd(&off[node], 1);
  elist[pos] = e;
}

// 4. Fused gather + MLP. One WAVE per node (16 waves / 1024-thread block).
//    Gather: 4 groups of 16 lanes each pull whole 256B attr rows (float4 per
//    lane, fully coalesced) for interleaved subsets of the node's edges;
//    xor-shuffle reduce across groups -> flow vector lives in registers
//    (lane l&15 holds features 4l..4l+3).
//    MLP: W1[64][128], W2[128][64] staged in LDS (64KB -> 2 blocks/CU =
//    32 waves/CU). Each lane owns h[lane], h[lane+64]; x[i]/h[k] broadcast
//    via __shfl; LDS reads are lane-consecutive (conflict-free).
__global__ __launch_bounds__(1024) void gather_mlp_kernel(
    const int* __restrict__ deg, const int* __restrict__ off_end,
    const int* __restrict__ elist, const float* __restrict__ attr,
    const float* __restrict__ W1, const float* __restrict__ b1,
    const float* __restrict__ W2, const float* __restrict__ b2,
    float* __restrict__ out, int N) {
  __shared__ float sW1[D_FEAT * H_HID];   // natural [i][k]
  __shared__ float sW2[H_HID * D_FEAT];   // natural [k][j]

  {
    float4* d1 = reinterpret_cast<float4*>(sW1);
    const float4* s1 = reinterpret_cast<const float4*>(W1);
    float4* d2 = reinterpret_cast<float4*>(sW2);
    const float4* s2 = reinterpret_cast<const float4*>(W2);
    for (int i = threadIdx.x; i < (D_FEAT * H_HID) / 4; i += 1024) {
      d1[i] = s1[i];
      d2[i] = s2[i];
    }
  }
  __syncthreads();

  int wave = threadIdx.x >> 6;
  int lane = threadIdx.x & 63;
  int n = blockIdx.x * 16 + wave;
  if (n >= N) return;

  int end = off_end[n];
  int cnt = deg[n];
  int start = end - cnt;
  int g = lane >> 4;   // edge subgroup 0..3
  int l = lane & 15;   // float4 slot within row

  float a0 = 0.f, a1 = 0.f, a2 = 0.f, a3 = 0.f;
  for (int p = start + g; p < end; p += 4) {
    int e = elist[p];  // uniform within the 16-lane group
    float4 v = reinterpret_cast<const float4*>(attr)[(size_t)e * 16 + l];
    a0 += v.x; a1 += v.y; a2 += v.z; a3 += v.w;
  }
  // Reduce the 4 subgroup partials; every lane ends with the full sum for
  // its feature slot.
  a0 += __shfl_xor(a0, 16); a0 += __shfl_xor(a0, 32);
  a1 += __shfl_xor(a1, 16); a1 += __shfl_xor(a1, 32);
  a2 += __shfl_xor(a2, 16); a2 += __shfl_xor(a2, 32);
  a3 += __shfl_xor(a3, 16); a3 += __shfl_xor(a3, 32);
  float a[4] = {a0, a1, a2, a3};

  // Phase 1: h = relu(x @ W1 + b1); lane owns h[lane], h[lane+64].
  float h0 = b1[lane];
  float h1 = b1[lane + 64];
#pragma unroll
  for (int i = 0; i < D_FEAT; ++i) {
    float xi = __shfl(a[i & 3], i >> 2);   // broadcast x[i]
    h0 = fmaf(xi, sW1[i * H_HID + lane], h0);
    h1 = fmaf(xi, sW1[i * H_HID + 64 + lane], h1);
  }
  h0 = fmaxf(h0, 0.f);
  h1 = fmaxf(h1, 0.f);

  // Phase 2: out[lane] = h @ W2[:,lane] + b2[lane].
  float acc = b2[lane];
#pragma unroll
  for (int k = 0; k < 64; ++k) {
    float hk = __shfl(h0, k);
    acc = fmaf(hk, sW2[k * D_FEAT + lane], acc);
  }
#pragma unroll
  for (int k = 0; k < 64; ++k) {
    float hk = __shfl(h1, k);
    acc = fmaf(hk, sW2[(k + 64) * D_FEAT + lane], acc);
  }
  out[(size_t)n * D_FEAT + lane] = acc;
}

// ---------------------------------------------------------------------------
// Launch
// ---------------------------------------------------------------------------
extern "C" void kernel_launch(void* const* d_in, const int* in_sizes, int n_in,
                              void* d_out, int out_size, void* d_ws, size_t ws_size,
                              hipStream_t stream) {
  const int*   edge_index = (const int*)d_in[0];    // [2, E]
  const float* edge_attr  = (const float*)d_in[1];  // [E, 64]
  const float* W1         = (const float*)d_in[3];  // [64, 128]
  const float* b1         = (const float*)d_in[4];  // [128]
  const float* W2         = (const float*)d_in[5];  // [128, 64]
  const float* b2         = (const float*)d_in[6];  // [64]
  float* out = (float*)d_out;

  const int E = in_sizes[1] / D_FEAT;   // 1,600,000
  const int N = out_size / D_FEAT;      // 100,000
  const int twoE = 2 * E;

  int* deg   = (int*)d_ws;      // [N]
  int* off   = deg + N;         // [N]
  int* elist = off + N;         // [2E]

  hipMemsetAsync(deg, 0, (size_t)N * sizeof(int), stream);
  count_deg_kernel<<<(twoE + 255) / 256, 256, 0, stream>>>(edge_index, deg, twoE);
  scan_kernel<<<1, SCAN_T, 0, stream>>>(deg, off, N);
  fill_kernel<<<(twoE + 255) / 256, 256, 0, stream>>>(edge_index, off, elist, E);

  int blocks = (N + 15) / 16;   // one wave per node, 16 waves/block
  gather_mlp_kernel<<<blocks, 1024, 0, stream>>>(deg, off, elist, edge_attr,
                                                 W1, b1, W2, b2, out, N);
}

// Round 3
// 1344.741 us; speedup vs baseline: 2.4354x; 1.3179x over previous
//
#include <hip/hip_runtime.h>
#include <cstdint>
#include <cstddef>

// Problem shape (fixed by the reference): E=1.6M, D=64, H=128, N=100k.
#define D_FEAT 64
#define H_HID 128

// ---------------------------------------------------------------------------
// Workspace (13.6 MB): deg[N], off[N], btot[1024], bbase[1024], elist[2E].
// flow[N][64] lives in d_out (gather writes it, MLP reads row n before
// overwriting row n -- same thread, program order).
// ---------------------------------------------------------------------------

// 1. Count incidences (3.2M int atomics into 400KB, L2-resident).
__global__ __launch_bounds__(256) void count_deg_kernel(
    const int* __restrict__ idx, int* __restrict__ deg, int twoE) {
  int t = blockIdx.x * 256 + threadIdx.x;
  if (t < twoE) atomicAdd(&deg[idx[t]], 1);
}

// 2a. Per-block (1024-wide) exclusive scan + block totals. 98 blocks run in
// parallel (vs round-2's single-WG serial scan).
__global__ __launch_bounds__(1024) void scanA_kernel(
    const int* __restrict__ deg, int* __restrict__ off,
    int* __restrict__ btot, int N) {
  __shared__ int s[1024];
  int i = blockIdx.x * 1024 + threadIdx.x;
  int v = (i < N) ? deg[i] : 0;
  s[threadIdx.x] = v;
  __syncthreads();
  for (int d = 1; d < 1024; d <<= 1) {
    int t = (threadIdx.x >= d) ? s[threadIdx.x - d] : 0;
    __syncthreads();
    s[threadIdx.x] += t;
    __syncthreads();
  }
  if (i < N) off[i] = s[threadIdx.x] - v;       // exclusive within block
  if (threadIdx.x == 1023) btot[blockIdx.x] = s[1023];
}

// 2b. Exclusive scan of block totals (nb <= 1024), one block.
__global__ __launch_bounds__(1024) void scanB_kernel(
    const int* __restrict__ btot, int* __restrict__ bbase, int nb) {
  __shared__ int s[1024];
  int v = (threadIdx.x < nb) ? btot[threadIdx.x] : 0;
  s[threadIdx.x] = v;
  __syncthreads();
  for (int d = 1; d < 1024; d <<= 1) {
    int t = (threadIdx.x >= d) ? s[threadIdx.x - d] : 0;
    __syncthreads();
    s[threadIdx.x] += t;
    __syncthreads();
  }
  if (threadIdx.x < nb) bbase[threadIdx.x] = s[threadIdx.x] - v;
}

// 2c. Add block bases -> global exclusive offsets.
__global__ __launch_bounds__(256) void scanC_kernel(
    int* __restrict__ off, const int* __restrict__ bbase, int N) {
  int i = blockIdx.x * 256 + threadIdx.x;
  if (i < N) off[i] += bbase[i >> 10];
}

// 3. Fill adjacency via destructive atomic cursors: afterwards off[n] is the
// END of node n's segment; start = off[n] - deg[n].
__global__ __launch_bounds__(256) void fill_kernel(
    const int* __restrict__ idx, int* __restrict__ off,
    int* __restrict__ elist, int E) {
  int t = blockIdx.x * 256 + threadIdx.x;
  if (t >= 2 * E) return;
  int node = idx[t];
  int e = (t < E) ? t : t - E;
  int pos = atomicAdd(&off[node], 1);
  elist[pos] = e;
}

// 4. Gather-only: one wave per node, 4 waves/block. 16-lane groups pull whole
// 256B attr rows (float4/lane, coalesced); xor-shuffle reduce; lanes 0..15
// store the 256B flow row. Tiny VGPR count -> high occupancy, pure memory.
__global__ __launch_bounds__(256) void gather_kernel(
    const int* __restrict__ deg, const int* __restrict__ off_end,
    const int* __restrict__ elist, const float* __restrict__ attr,
    float* __restrict__ flow, int N) {
  int wave = threadIdx.x >> 6;
  int lane = threadIdx.x & 63;
  int n = blockIdx.x * 4 + wave;
  if (n >= N) return;

  int end = off_end[n];
  int start = end - deg[n];
  int g = lane >> 4;   // edge subgroup 0..3
  int l = lane & 15;   // float4 slot within the 256B row

  float a0 = 0.f, a1 = 0.f, a2 = 0.f, a3 = 0.f;
  int p = start + g;
  // 2-wide unroll: two independent row-loads in flight per iteration.
  for (; p + 4 < end; p += 8) {
    int e0 = elist[p];
    int e1 = elist[p + 4];
    float4 v0 = reinterpret_cast<const float4*>(attr)[(size_t)e0 * 16 + l];
    float4 v1 = reinterpret_cast<const float4*>(attr)[(size_t)e1 * 16 + l];
    a0 += v0.x + v1.x; a1 += v0.y + v1.y;
    a2 += v0.z + v1.z; a3 += v0.w + v1.w;
  }
  if (p < end) {
    int e0 = elist[p];
    float4 v0 = reinterpret_cast<const float4*>(attr)[(size_t)e0 * 16 + l];
    a0 += v0.x; a1 += v0.y; a2 += v0.z; a3 += v0.w;
  }
  a0 += __shfl_xor(a0, 16); a0 += __shfl_xor(a0, 32);
  a1 += __shfl_xor(a1, 16); a1 += __shfl_xor(a1, 32);
  a2 += __shfl_xor(a2, 16); a2 += __shfl_xor(a2, 32);
  a3 += __shfl_xor(a3, 16); a3 += __shfl_xor(a3, 32);

  if (g == 0) {  // lanes 0..15 write the full 256B row (deg==0 -> zeros)
    reinterpret_cast<float4*>(flow)[(size_t)n * 16 + l] =
        make_float4(a0, a1, a2, a3);
  }
}

// 5. MLP: thread-per-node, h[128] in registers, NO shuffles. All weight reads
// are wave-broadcast ds_read_b128 (64 wave-LDS-ops per node vs 456 in the
// round-2 shuffle scheme). W2 staged transposed so phase 2 reads contiguous.
// Reads its x row from `flow` (== out) before overwriting it.
__global__ __launch_bounds__(256, 2) void mlp_kernel(
    const float* __restrict__ W1, const float* __restrict__ b1,
    const float* __restrict__ W2, const float* __restrict__ b2,
    float* __restrict__ out, int N) {
  __shared__ float sW1[D_FEAT * H_HID];   // [i][k] natural
  __shared__ float sW2t[D_FEAT * H_HID];  // [j][k] = W2[k][j]
  __shared__ float sB1[H_HID];
  __shared__ float sB2[D_FEAT];

  {
    float4* dst = reinterpret_cast<float4*>(sW1);
    const float4* src = reinterpret_cast<const float4*>(W1);
    for (int i = threadIdx.x; i < (D_FEAT * H_HID) / 4; i += 256) dst[i] = src[i];
  }
  for (int t = threadIdx.x; t < H_HID * D_FEAT; t += 256) {
    int k = t >> 6;
    int j = t & 63;
    sW2t[j * H_HID + k] = W2[t];   // one-time strided write, negligible
  }
  if (threadIdx.x < H_HID) sB1[threadIdx.x] = b1[threadIdx.x];
  if (threadIdx.x < D_FEAT) sB2[threadIdx.x] = b2[threadIdx.x];
  __syncthreads();

  int n = blockIdx.x * 256 + threadIdx.x;
  if (n >= N) return;

  const float4* xg = reinterpret_cast<const float4*>(out + (size_t)n * D_FEAT);

  float h[H_HID];
#pragma unroll
  for (int k = 0; k < H_HID; ++k) h[k] = sB1[k];

  // Phase 1: h += x @ W1. Outer loop dynamic (code size), inner unrolled.
  for (int ii = 0; ii < 16; ++ii) {
    float4 x4 = xg[ii];
#pragma unroll
    for (int u = 0; u < 4; ++u) {
      float xi = (u == 0) ? x4.x : (u == 1) ? x4.y : (u == 2) ? x4.z : x4.w;
      const float* w = &sW1[(ii * 4 + u) * H_HID];
#pragma unroll
      for (int k = 0; k < H_HID; ++k) h[k] = fmaf(xi, w[k], h[k]);  // b128s
    }
  }
#pragma unroll
  for (int k = 0; k < H_HID; ++k) h[k] = fmaxf(h[k], 0.f);

  // Phase 2: 4 outputs at a time -> float4 store.
  float4* outg = reinterpret_cast<float4*>(out + (size_t)n * D_FEAT);
  for (int jj = 0; jj < 16; ++jj) {
    float a0 = sB2[jj * 4 + 0], a1 = sB2[jj * 4 + 1];
    float a2 = sB2[jj * 4 + 2], a3 = sB2[jj * 4 + 3];
    const float* w0 = &sW2t[(jj * 4 + 0) * H_HID];
    const float* w1 = &sW2t[(jj * 4 + 1) * H_HID];
    const float* w2 = &sW2t[(jj * 4 + 2) * H_HID];
    const float* w3 = &sW2t[(jj * 4 + 3) * H_HID];
#pragma unroll
    for (int k = 0; k < H_HID; ++k) {
      float hk = h[k];
      a0 = fmaf(hk, w0[k], a0);
      a1 = fmaf(hk, w1[k], a1);
      a2 = fmaf(hk, w2[k], a2);
      a3 = fmaf(hk, w3[k], a3);
    }
    outg[jj] = make_float4(a0, a1, a2, a3);
  }
}

// ---------------------------------------------------------------------------
// Launch
// ---------------------------------------------------------------------------
extern "C" void kernel_launch(void* const* d_in, const int* in_sizes, int n_in,
                              void* d_out, int out_size, void* d_ws, size_t ws_size,
                              hipStream_t stream) {
  const int*   edge_index = (const int*)d_in[0];    // [2, E]
  const float* edge_attr  = (const float*)d_in[1];  // [E, 64]
  const float* W1         = (const float*)d_in[3];  // [64, 128]
  const float* b1         = (const float*)d_in[4];  // [128]
  const float* W2         = (const float*)d_in[5];  // [128, 64]
  const float* b2         = (const float*)d_in[6];  // [64]
  float* out = (float*)d_out;

  const int E = in_sizes[1] / D_FEAT;   // 1,600,000
  const int N = out_size / D_FEAT;      // 100,000
  const int twoE = 2 * E;
  const int nb = (N + 1023) / 1024;     // 98 scan blocks

  int* deg   = (int*)d_ws;      // [N]
  int* off   = deg + N;         // [N]
  int* btot  = off + N;         // [1024]
  int* bbase = btot + 1024;     // [1024]
  int* elist = bbase + 1024;    // [2E]

  hipMemsetAsync(deg, 0, (size_t)N * sizeof(int), stream);
  count_deg_kernel<<<(twoE + 255) / 256, 256, 0, stream>>>(edge_index, deg, twoE);
  scanA_kernel<<<nb, 1024, 0, stream>>>(deg, off, btot, N);
  scanB_kernel<<<1, 1024, 0, stream>>>(btot, bbase, nb);
  scanC_kernel<<<(N + 255) / 256, 256, 0, stream>>>(off, bbase, N);
  fill_kernel<<<(twoE + 255) / 256, 256, 0, stream>>>(edge_index, off, elist, E);

  gather_kernel<<<(N + 3) / 4, 256, 0, stream>>>(deg, off, elist, edge_attr,
                                                 out, N);
  mlp_kernel<<<(N + 255) / 256, 256, 0, stream>>>(W1, b1, W2, b2, out, N);
}